// Round 4
// baseline (110.568 us; speedup 1.0000x reference)
//
#include <hip/hip_runtime.h>
#include <hip/hip_bf16.h>

// DCellLinear: y[s] = x[s] @ W[s]^T + b[s], s = 0..4095 (f32 in/out, bf16 MFMA)
// 539 MB irreducible @ ~6.3 TB/s => ~86 us floor. R1-R3 all ~108-111 us at the
// load->compute->store per-block phase structure => phase serialization is the gap.
// R4: persistent 2-deep pipeline. 512 blocks x 512 thr (8 waves), 8 subsystems per
// block. LDS: 2 x 48 KB bf16 panels (x 16K + W 32K, XOR-swizzled rows). Per iter:
//   issue reg-loads(s+2)  ->  compute+store(s) from lds[buf]  ->
//   cvt+ds_write(s+1) into lds[buf^1]  ->  barrier.
// Loads stay in flight across barriers (T14, r277): HBM queues never drain.

typedef __attribute__((ext_vector_type(8))) short bf16x8;
typedef __attribute__((ext_vector_type(4))) float f32x4;

constexpr int NSUB = 4096, BATCH = 64, DIN = 128, DOUT = 128;
constexpr int SPB   = 8;            // subsystems per block
constexpr int NBLK  = NSUB / SPB;   // 512 blocks
constexpr int PANEL = 49152;        // 48 KB: x-bf16 16K @0, W-bf16 32K @16384

__device__ __forceinline__ unsigned pk2(float lo, float hi) {
    __hip_bfloat162 h = __float22bfloat162_rn(make_float2(lo, hi));  // v_cvt_pk_bf16_f32
    unsigned u; __builtin_memcpy(&u, &h, 4);
    return u;
}

struct Stg { f32x4 x[4]; f32x4 w[8]; };   // 96 KB/block staged as regs (48 VGPR)

__global__ __launch_bounds__(512, 2)
void dcell(const float* __restrict__ X, const float* __restrict__ W,
           const float* __restrict__ Bv, float* __restrict__ Y)
{
    __shared__ __align__(16) char lds[2][PANEL];
    const int tid  = threadIdx.x;
    const int lane = tid & 63;
    const int wv   = tid >> 6;     // 8 waves
    const int qw   = lane >> 4;
    const int lr   = lane & 15;
    const int n0   = wv * 16;      // wave's 16 output cols
    const int sb   = blockIdx.x * SPB;

    auto loadStg = [&](int s, Stg& r) {
        const float* xp = X + (size_t)s * (BATCH * DIN);
        const float* wp = W + (size_t)s * (DOUT * DIN);
        #pragma unroll
        for (int i = 0; i < 4; ++i) r.x[i] = *(const f32x4*)(xp + 4 * (tid + 512 * i));
        #pragma unroll
        for (int i = 0; i < 8; ++i) r.w[i] = *(const f32x4*)(wp + 4 * (tid + 512 * i));
    };
    // cvt f32->bf16 and write swizzled panels: row stride 256 B, byte ^= (row&7)<<4
    auto writeStg = [&](int b, const Stg& r) {
        #pragma unroll
        for (int i = 0; i < 4; ++i) {
            const int e = 4 * (tid + 512 * i), row = e >> 7, colb = (e & 127) * 2;
            uint2 p; p.x = pk2(r.x[i][0], r.x[i][1]); p.y = pk2(r.x[i][2], r.x[i][3]);
            *(uint2*)(lds[b] + row * 256 + (colb ^ ((row & 7) << 4))) = p;
        }
        #pragma unroll
        for (int i = 0; i < 8; ++i) {
            const int e = 4 * (tid + 512 * i), row = e >> 7, colb = (e & 127) * 2;
            uint2 p; p.x = pk2(r.w[i][0], r.w[i][1]); p.y = pk2(r.w[i][2], r.w[i][3]);
            *(uint2*)(lds[b] + 16384 + row * 256 + (colb ^ ((row & 7) << 4))) = p;
        }
    };
    auto computeStore = [&](int s, int b) {
        const float bb = Bv[(size_t)s * DOUT + n0 + lr];   // early issue, used at store
        f32x4 acc[4];
        #pragma unroll
        for (int mt = 0; mt < 4; ++mt) {
            acc[mt][0] = 0.f; acc[mt][1] = 0.f; acc[mt][2] = 0.f; acc[mt][3] = 0.f;
        }
        #pragma unroll
        for (int ks = 0; ks < 4; ++ks) {
            const int cb = (ks * 32 + qw * 8) * 2;
            const int rb = n0 + lr;
            const bf16x8 bfr = *(const bf16x8*)(
                lds[b] + 16384 + rb * 256 + (cb ^ ((rb & 7) << 4)));
            #pragma unroll
            for (int mt = 0; mt < 4; ++mt) {
                const int ra = mt * 16 + lr;
                const bf16x8 afr = *(const bf16x8*)(
                    lds[b] + ra * 256 + (cb ^ ((ra & 7) << 4)));
                acc[mt] = __builtin_amdgcn_mfma_f32_16x16x32_bf16(
                    afr, bfr, acc[mt], 0, 0, 0);
            }
        }
        // C/D: col = n0+lr (lanes), row = mt*16 + qw*4 + j  [m89]
        float* od = Y + (size_t)s * (BATCH * DOUT) + n0 + lr;
        #pragma unroll
        for (int mt = 0; mt < 4; ++mt)
            #pragma unroll
            for (int j = 0; j < 4; ++j)
                od[(size_t)(mt * 16 + qw * 4 + j) * DOUT] = acc[mt][j] + bb;
    };

    // prologue: fill pipe 2 deep, write s0 panel
    Stg rA, rB;
    loadStg(sb + 0, rA);
    loadStg(sb + 1, rB);
    writeStg(0, rA);
    __syncthreads();

    #pragma unroll
    for (int tt = 0; tt < SPB; tt += 2) {
        // even t = tt (buf 0): rA free -> load s+2; rB (s+1) arrived -> write buf 1
        if (tt + 2 < SPB) loadStg(sb + tt + 2, rA);
        computeStore(sb + tt, 0);
        writeStg(1, rB);
        __syncthreads();
        // odd t = tt+1 (buf 1): rB free -> load s+3; rA -> write buf 0
        if (tt + 3 < SPB) loadStg(sb + tt + 3, rB);
        computeStore(sb + tt + 1, 1);
        if (tt + 2 < SPB) writeStg(0, rA);
        __syncthreads();
    }
}

extern "C" void kernel_launch(void* const* d_in, const int* in_sizes, int n_in,
                              void* d_out, int out_size, void* d_ws, size_t ws_size,
                              hipStream_t stream) {
    const float* X  = (const float*)d_in[0];
    const float* W  = (const float*)d_in[1];
    const float* Bv = (const float*)d_in[2];
    float*       Y  = (float*)d_out;
    dcell<<<NBLK, 512, 0, stream>>>(X, W, Bv, Y);
}

// Round 5
// 92.348 us; speedup vs baseline: 1.1973x; 1.1973x over previous
//
#include <hip/hip_runtime.h>
#include <hip/hip_bf16.h>

// DCellLinear: y[s] = x[s] @ W[s]^T + b[s], s = 0..4095 (f32 in/out, bf16 MFMA)
// 539 MB irreducible. R1-R4 (four disjoint schedules) all 108-111 us = ~5.0 TB/s.
// R5 = R3 (best, 108.25) + NONTEMPORAL hints on every global access: each byte is
// touched exactly once, so L2/L3 allocation is pure pollution; nt-bit loads/stores
// test whether eviction/writeback serialization is the 5.0-vs-6.3 TB/s gap.

typedef __attribute__((ext_vector_type(8))) short bf16x8;
typedef __attribute__((ext_vector_type(4))) float f32x4;

constexpr int NSUB = 4096, BATCH = 64, DIN = 128, DOUT = 128;
constexpr int XOFF = 0;        // x panel [64 rows][256 B bf16]  = 16 KB
constexpr int WOFF = 16384;    // W panel [128 rows][256 B bf16] = 32 KB

__device__ __forceinline__ unsigned pk2(float lo, float hi) {
    __hip_bfloat162 h = __float22bfloat162_rn(make_float2(lo, hi));  // v_cvt_pk_bf16_f32
    unsigned u; __builtin_memcpy(&u, &h, 4);
    return u;
}
__device__ __forceinline__ f32x4 ntld(const float* p) {
    return __builtin_nontemporal_load(reinterpret_cast<const f32x4*>(p));
}
__device__ __forceinline__ void ntst(float* p, f32x4 v) {
    __builtin_nontemporal_store(v, reinterpret_cast<f32x4*>(p));
}

__global__ __launch_bounds__(256, 3)
void dcell(const float* __restrict__ X, const float* __restrict__ W,
           const float* __restrict__ Bv, float* __restrict__ Y)
{
    __shared__ __align__(16) char lds[49152];
    const int s    = blockIdx.x;
    const int tid  = threadIdx.x;
    const int lane = tid & 63;
    const int wv   = tid >> 6;
    const int qw   = lane >> 4;
    const int lr   = lane & 15;
    const int n0   = wv * 32;          // wave's 32 output cols

    const float* xsrc = X + (size_t)s * (BATCH * DIN);
    const float* wsrc = W + (size_t)s * (DOUT * DIN);

    // ---- all global reads as linear nt bursts (1 KB/wave-instr) ----
    f32x4 xr[8], wr[16];
    #pragma unroll
    for (int i = 0; i < 8; ++i)  xr[i] = ntld(xsrc + 4 * (tid + 256 * i));
    #pragma unroll
    for (int i = 0; i < 16; ++i) wr[i] = ntld(wsrc + 4 * (tid + 256 * i));

    // ---- bias -> accumulators (C/D: col=lane&15, row=qw*4+reg [m89]) ----
    f32x4 acc[4][2];
    {
        const float* bs = Bv + (size_t)s * DOUT + n0;
        #pragma unroll
        for (int nt = 0; nt < 2; ++nt) {
            const float bb = bs[nt * 16 + lr];
            #pragma unroll
            for (int mt = 0; mt < 4; ++mt) {
                acc[mt][nt][0] = bb; acc[mt][nt][1] = bb;
                acc[mt][nt][2] = bb; acc[mt][nt][3] = bb;
            }
        }
    }

    // ---- cvt f32->bf16, write swizzled panels (byte ^= (row&7)<<4) ----
    #pragma unroll
    for (int i = 0; i < 8; ++i) {
        const int c = tid + 256 * i, row = c >> 5, colb = (c & 31) * 8;
        uint2 p; p.x = pk2(xr[i][0], xr[i][1]); p.y = pk2(xr[i][2], xr[i][3]);
        *reinterpret_cast<uint2*>(lds + XOFF + row * 256 + (colb ^ ((row & 7) << 4))) = p;
    }
    #pragma unroll
    for (int i = 0; i < 16; ++i) {
        const int c = tid + 256 * i, row = c >> 5, colb = (c & 31) * 8;
        uint2 p; p.x = pk2(wr[i][0], wr[i][1]); p.y = pk2(wr[i][2], wr[i][3]);
        *reinterpret_cast<uint2*>(lds + WOFF + row * 256 + (colb ^ ((row & 7) << 4))) = p;
    }
    __syncthreads();

    // ---- 4 MFMA k-steps, all operands from LDS ----
    #pragma unroll
    for (int k0 = 0; k0 < DIN; k0 += 32) {
        bf16x8 bfr[2];
        #pragma unroll
        for (int nt = 0; nt < 2; ++nt) {
            const int row = n0 + nt * 16 + lr;
            const int colb = ((k0 + qw * 8) * 2) ^ ((row & 7) << 4);
            bfr[nt] = *reinterpret_cast<const bf16x8*>(lds + WOFF + row * 256 + colb);
        }
        #pragma unroll
        for (int mt = 0; mt < 4; ++mt) {
            const int row = mt * 16 + lr;
            const int colb = ((k0 + qw * 8) * 2) ^ ((row & 7) << 4);
            const bf16x8 afr = *reinterpret_cast<const bf16x8*>(lds + XOFF + row * 256 + colb);
            #pragma unroll
            for (int nt = 0; nt < 2; ++nt)
                acc[mt][nt] = __builtin_amdgcn_mfma_f32_16x16x32_bf16(
                    afr, bfr[nt], acc[mt][nt], 0, 0, 0);
        }
    }
    __syncthreads();   // panels dead; LDS reused for accumulator transpose

    // ---- acc -> per-wave f32 slab [64][36] (pad 4 kills write conflicts) ----
    float* slab = reinterpret_cast<float*>(lds) + wv * 2304;
    #pragma unroll
    for (int mt = 0; mt < 4; ++mt)
        #pragma unroll
        for (int j = 0; j < 4; ++j) {
            const int row = mt * 16 + qw * 4 + j;
            #pragma unroll
            for (int nt = 0; nt < 2; ++nt)
                slab[row * 36 + nt * 16 + lr] = acc[mt][nt][j];
        }
    __syncthreads();

    // ---- fully-linear nt stores: 32 KB contiguous per block ----
    float* od = Y + (size_t)s * (BATCH * DOUT);
    const float* lf = reinterpret_cast<const float*>(lds);
    #pragma unroll
    for (int i = 0; i < 8; ++i) {
        const int c = tid + 256 * i;            // f32x4 chunk in [64][128]
        const int row = c >> 5, col4 = (c & 31) * 4;
        const f32x4 v = *reinterpret_cast<const f32x4*>(
            lf + (col4 >> 5) * 2304 + row * 36 + (col4 & 31));
        ntst(od + 4 * c, v);
    }
}

extern "C" void kernel_launch(void* const* d_in, const int* in_sizes, int n_in,
                              void* d_out, int out_size, void* d_ws, size_t ws_size,
                              hipStream_t stream) {
    const float* X  = (const float*)d_in[0];
    const float* W  = (const float*)d_in[1];
    const float* Bv = (const float*)d_in[2];
    float*       Y  = (float*)d_out;
    dcell<<<NSUB, 256, 0, stream>>>(X, W, Bv, Y);
}